// Round 12
// baseline (14658.937 us; speedup 1.0000x reference)
//
#include <hip/hip_runtime.h>

#define TT 1024
#define DDIM 6
#define HH 256
#define AGSCOPE __HIP_MEMORY_SCOPE_AGENT

typedef float f4v __attribute__((ext_vector_type(4)));
typedef float f2v __attribute__((ext_vector_type(2)));
typedef short s8v __attribute__((ext_vector_type(8)));
typedef unsigned int u32;
typedef unsigned short u16;

// grid: 1024 blocks = 16 batch-domains (bg = blk>>6, 16 batches) x 64 tile-groups (gy = blk&63,
// 4 units = 16 gate-rows). block: 192 threads = 3 waves = the 3 MFMA PLANES of R8's numerics:
//   wid0 (A): Whi x hhi   wid1 (B): Whi x hlo   wid2 (C): Wlo x hhi
// Gate value = (aA + aB) + aC combined by wave A from LDS partials -> per-output arithmetic is
// BIT-IDENTICAL to R8 (same bf16 plane bits, same chunk order c=0..7 / c=0..15, same fp32 add
// order, same cvt) -> absmax must reproduce R8's 4.882812e-4.
// Occupancy: 4 blocks/CU x 3 waves = 12 waves/CU (3/SIMD); co-resident blocks {blk,+256,+512,+768}
// have bg {b,b+4,b+8,b+12} -> 4 independent barrier domains per CU: stalls hide under other
// domains' MFMAs (R10's proven lever, without its fp16 denormal cost).
// Slabs [2 dbuf][16 bg][4096 u16], idx(u,b) = (u>>5)*512 + ((u>>3)&3)*128 + b*8 + (u&7);
// frag-linear identity copy; stage aux=17 (sc0|sc1, L3-fresh); write-through agent stores;
// u16 flag barrier; no invalidates (R8-proven protocol).

__device__ __forceinline__ float sigf(float x) {
    return __builtin_amdgcn_rcpf(1.0f + __expf(-x));
}
__device__ __forceinline__ float tanhf_fast(float x) {
    return fmaf(2.0f, __builtin_amdgcn_rcpf(1.0f + __expf(-2.0f * x)), -1.0f);
}
__device__ __forceinline__ void st_agent_u16(u16* p, u16 v) {
    __hip_atomic_store(p, v, __ATOMIC_RELAXED, AGSCOPE);
}

#define MFMA(a, b, c) __builtin_amdgcn_mfma_f32_16x16x32_bf16(a, b, c, 0, 0, 0)

// f32 -> bf16 hi (RNE) + bf16 lo (RNE of residual)  [R8 verbatim]
__device__ __forceinline__ void cvt_hl(float v, u16& hi, u16& lo) {
    u32 u = __float_as_uint(v);
    u32 r = (u + 0x7fffu + ((u >> 16) & 1u)) & 0xffff0000u;
    hi = (u16)(r >> 16);
    float lof = v - __uint_as_float(r);
    u32 u2 = __float_as_uint(lof);
    lo = (u16)((u2 + 0x7fffu + ((u2 >> 16) & 1u)) >> 16);
}
__device__ __forceinline__ void pack8_hl(const float* __restrict__ p, s8v& hi, s8v& lo) {
    #pragma unroll
    for (int j = 0; j < 8; ++j) {
        u16 h, l;
        cvt_hl(p[j], h, l);
        hi[j] = (short)h;
        lo[j] = (short)l;
    }
}

// async 16B/lane global->LDS copy; aux=17 = sc0|sc1 (read at L3 coherence point)
__device__ __forceinline__ void stage16(const u16* g, u16* lds) {
    __builtin_amdgcn_global_load_lds(
        (const __attribute__((address_space(1))) u32*)g,
        (__attribute__((address_space(3))) u32*)lds, 16, 0, 17);
}

__device__ __forceinline__ void group_barrier(u16* flags, int bg, int token) {
    __syncthreads();                      // drains vmcnt -> h stores at L3
    asm volatile("" ::: "memory");
    if (threadIdx.x == 0) {
        __hip_atomic_store(&flags[blockIdx.x], (u16)token, __ATOMIC_RELAXED, AGSCOPE);
    }
    if (threadIdx.x < 64) {               // 64 peers share bg
        while ((int)__hip_atomic_load(&flags[(bg << 6) + (int)threadIdx.x], __ATOMIC_RELAXED,
                                      AGSCOPE) < token) {
            __builtin_amdgcn_s_sleep(1);
        }
    }
    __syncthreads();
    asm volatile("" ::: "memory");
}

// 192-thread emit: waves 0,1 (tid<128) cover units tid and tid+128; Wo read from global (L1-hot)
__device__ __forceinline__ void emit_outg(float h0, float h1v,
                                          const float* __restrict__ W_out,
                                          float (*redsc)[8],
                                          float boV,
                                          float* __restrict__ op, int tid) {
    float p[6];
    if (tid < 128) {
        #pragma unroll
        for (int d = 0; d < 6; ++d) {
            p[d] = W_out[d * HH + tid] * h0 + W_out[d * HH + tid + 128] * h1v;
        }
        #pragma unroll
        for (int off = 1; off < 64; off <<= 1) {
            #pragma unroll
            for (int d = 0; d < 6; ++d) p[d] += __shfl_xor(p[d], off);
        }
        if ((tid & 63) == 0) {
            #pragma unroll
            for (int d = 0; d < 6; ++d) redsc[tid >> 6][d] = p[d];
        }
    }
    __syncthreads();
    if (tid < 6) {
        op[tid] = redsc[0][tid] + redsc[1][tid] + boV;
    }
}

__global__ __launch_bounds__(192, 3) void lstm_persist(
    const float* __restrict__ x,
    const float* __restrict__ W_ih1, const float* __restrict__ W_hh1,
    const float* __restrict__ b_ih1, const float* __restrict__ b_hh1,
    const float* __restrict__ W_ih2, const float* __restrict__ W_hh2,
    const float* __restrict__ b_ih2, const float* __restrict__ b_hh2,
    const float* __restrict__ W_out, const float* __restrict__ b_out,
    float* __restrict__ out,
    u16* __restrict__ flags,
    u16* __restrict__ B1h, u16* __restrict__ B1l,
    u16* __restrict__ B2h, u16* __restrict__ B2l)
{
    __shared__ u16 sB1h[8][64][8], sB1l[8][64][8];   // 8KB each, frag-linear
    __shared__ u16 sB2h[8][64][8], sB2l[8][64][8];
    __shared__ f4v pscr1[2][64], pscr5[2][64];       // plane partials (P1 / P5), separate buffers
    __shared__ float redsc[2][8];

    const int tid = threadIdx.x;
    const int blk = blockIdx.x;
    const int bg  = blk >> 6;              // batch-domain (16 batches)
    const int gy  = blk & 63;              // tile-group (4 units)
    const int wid = tid >> 6;              // plane: 0=A(hi.hi) 1=B(hi.lo) 2=C(lo.hi)
    const int l   = tid & 63;
    const int kl  = (l >> 4) << 3;         // lane k-offset within 32-chunk
    // A-operand lane: row r16 = l&15 in tile; row = du*4 + gate (R6-verified map)
    const int r16  = l & 15;
    const int gr_a = (r16 & 3) * HH + (gy << 2) + (r16 >> 2);
    // D-owner lane (plane A): unit du = l>>4 (0..3), batch db = l&15
    const int du       = l >> 4;
    const int db       = l & 15;
    const int unit_abs = (gy << 2) + du;
    const int db_abs   = (bg << 4) + db;
    const bool emitWG  = (gy < 16);
    const int ro       = (bg << 4) + gy;   // emitted batch row (emitWG only)

    const int so_base = (unit_abs >> 5) * 512 + ((unit_abs >> 3) & 3) * 128
                      + db * 8 + (unit_abs & 7);
    // emit read offsets for units u=tid, u=tid+128 (b_local = gy)
    const int eo0 = (tid >> 5) * 512 + (((tid >> 3) & 3) * 128) + gy * 8 + (tid & 7);
    const int u1  = tid + 128;
    const int eo1 = (u1 >> 5) * 512 + (((u1 >> 3) & 3) * 128) + gy * 8 + (u1 & 7);

    // ---- prologue: zero slabs (h(0)=0) ----
    for (int i = tid; i < 2048; i += 192) {
        ((u32*)sB1h)[i] = 0u; ((u32*)sB1l)[i] = 0u;
        ((u32*)sB2h)[i] = 0u; ((u32*)sB2l)[i] = 0u;
    }

    // ---- A-fragments: this wave's plane only (bit-exact bf16 planes, R8 cvt) ----
    s8v P1f[8], P5f[16];
    #pragma unroll
    for (int c = 0; c < 8; ++c) {
        s8v hi, lo;
        pack8_hl(W_hh1 + gr_a * HH + c * 32 + kl, hi, lo);
        P1f[c] = (wid == 2) ? lo : hi;
    }
    #pragma unroll
    for (int c = 0; c < 8; ++c) {
        s8v hi, lo;
        pack8_hl(W_ih2 + gr_a * HH + c * 32 + kl, hi, lo);
        P5f[c] = (wid == 2) ? lo : hi;
    }
    #pragma unroll
    for (int c = 0; c < 8; ++c) {
        s8v hi, lo;
        pack8_hl(W_hh2 + gr_a * HH + c * 32 + kl, hi, lo);
        P5f[8 + c] = (wid == 2) ? lo : hi;
    }
    // B-operand plane source: A,C read hi; B reads lo
    const u16* sb1B = (wid == 1) ? &sB1l[0][0][0] : &sB1h[0][0][0];
    const u16* sb2B = (wid == 1) ? &sB2l[0][0][0] : &sB2h[0][0][0];

    // ---- D-owner constants (plane A only) ----
    float b1a[4], b2a[4], Wxr[4][6];
    float c1 = 0.0f, c2 = 0.0f;
    f2v xA = {0.f, 0.f}, xB = {0.f, 0.f}, xC = {0.f, 0.f};
    const float* xbase = x + (size_t)db_abs * (TT * DDIM);
    if (wid == 0) {
        #pragma unroll
        for (int g = 0; g < 4; ++g) {
            const int gr = g * HH + unit_abs;
            b1a[g] = b_ih1[gr] + b_hh1[gr];
            b2a[g] = b_ih2[gr] + b_hh2[gr];
            #pragma unroll
            for (int d = 0; d < 6; ++d) Wxr[g][d] = W_ih1[gr * DDIM + d];
        }
        xA = *(const f2v*)(xbase);
        xB = *(const f2v*)(xbase + 2);
        xC = *(const f2v*)(xbase + 4);
    }
    const float boV = (tid < 6) ? b_out[tid] : 0.0f;
    __syncthreads();

    #pragma unroll 1
    for (int t = 0; t < TT; ++t) {
        const int cur = t & 1, prv = cur ^ 1;

        // ---- P1: each wave accumulates ITS plane over chunks 0..7 (R8 chunk order) ----
        f4v a = {0.f, 0.f, 0.f, 0.f};
        #pragma unroll
        for (int c = 0; c < 8; ++c) {
            const s8v v = *(const s8v*)(sb1B + c * 512 + l * 8);
            a = MFMA(P1f[c], v, a);
        }
        if (wid) pscr1[wid - 1][l] = a;
        __syncthreads();                                   // S1: partials ready
        if (wid == 0) {
            const f4v acc = (a + pscr1[0][l]) + pscr1[1][l];   // (aA+aB)+aC, R8 order
            float ga[4];
            #pragma unroll
            for (int g = 0; g < 4; ++g) {
                float v = acc[g] + b1a[g];
                v = fmaf(Wxr[g][0], xA.x, v); v = fmaf(Wxr[g][1], xA.y, v);
                v = fmaf(Wxr[g][2], xB.x, v); v = fmaf(Wxr[g][3], xB.y, v);
                v = fmaf(Wxr[g][4], xC.x, v); v = fmaf(Wxr[g][5], xC.y, v);
                ga[g] = v;
            }
            const float i1 = sigf(ga[0]), f1 = sigf(ga[1]);
            const float g1 = tanhf_fast(ga[2]), o1 = sigf(ga[3]);
            c1 = fmaf(f1, c1, i1 * g1);
            const float h1v = o1 * tanhf_fast(c1);
            u16 hh, hl;
            cvt_hl(h1v, hh, hl);
            const int idx = (cur * 16 + bg) * 4096 + so_base;
            st_agent_u16(&B1h[idx], hh);
            st_agent_u16(&B1l[idx], hl);
        }

        // publish h1(t) (+ h2(t-1) stored last step) across the 64-WG domain
        group_barrier(flags, bg, t + 1);

        // ---- stage slabs (identity copy): wid0->B1h, wid1->B1l, wid2->B2h+B2l ----
        if (wid == 0) {
            const u16* g = B1h + (cur * 16 + bg) * 4096;
            #pragma unroll
            for (int i = 0; i < 8; ++i) stage16(g + i * 512 + l * 8, &sB1h[0][0][0] + i * 512);
        } else if (wid == 1) {
            const u16* g = B1l + (cur * 16 + bg) * 4096;
            #pragma unroll
            for (int i = 0; i < 8; ++i) stage16(g + i * 512 + l * 8, &sB1l[0][0][0] + i * 512);
        } else if (t > 0) {
            const u16* gh2 = B2h + (prv * 16 + bg) * 4096;
            const u16* gl2 = B2l + (prv * 16 + bg) * 4096;
            #pragma unroll
            for (int i = 0; i < 8; ++i) stage16(gh2 + i * 512 + l * 8, &sB2h[0][0][0] + i * 512);
            #pragma unroll
            for (int i = 0; i < 8; ++i) stage16(gl2 + i * 512 + l * 8, &sB2l[0][0][0] + i * 512);
        }

        // x(t+1) register prefetch (plane A; overlaps stage latency)
        if (wid == 0 && t + 1 < TT) {
            const float* xnp = xbase + (t + 1) * DDIM;
            xA = *(const f2v*)(xnp);
            xB = *(const f2v*)(xnp + 2);
            xC = *(const f2v*)(xnp + 4);
        }

        __syncthreads();   // S4: stage complete (vmcnt drained)

        // ---- emit out(t-1) from staged LDS slab (uniform branch) ----
        if (emitWG && t > 0) {
            const float h0 = __uint_as_float((u32)(((const u16*)sB2h)[eo0]) << 16)
                           + __uint_as_float((u32)(((const u16*)sB2l)[eo0]) << 16);
            const float h1v = __uint_as_float((u32)(((const u16*)sB2h)[eo1]) << 16)
                            + __uint_as_float((u32)(((const u16*)sB2l)[eo1]) << 16);
            emit_outg(h0, h1v, W_out, redsc, boV, out + ro * (TT * DDIM) + (t - 1) * DDIM, tid);
        }

        // ---- P5: plane chains over 16 chunks (W_ih2 x h1(t), then W_hh2 x h2(t-1)) ----
        f4v e = {0.f, 0.f, 0.f, 0.f};
        #pragma unroll
        for (int c = 0; c < 8; ++c) {
            const s8v v = *(const s8v*)(sb1B + c * 512 + l * 8);
            e = MFMA(P5f[c], v, e);
        }
        #pragma unroll
        for (int c = 0; c < 8; ++c) {
            const s8v v = *(const s8v*)(sb2B + c * 512 + l * 8);
            e = MFMA(P5f[8 + c], v, e);
        }
        if (wid) pscr5[wid - 1][l] = e;
        __syncthreads();                                   // S6: partials ready
        if (wid == 0) {
            const f4v acc2 = (e + pscr5[0][l]) + pscr5[1][l];
            const float i2  = sigf(acc2[0] + b2a[0]);
            const float f2g = sigf(acc2[1] + b2a[1]);
            const float g2  = tanhf_fast(acc2[2] + b2a[2]);
            const float o2  = sigf(acc2[3] + b2a[3]);
            c2 = fmaf(f2g, c2, i2 * g2);
            const float h2v = o2 * tanhf_fast(c2);
            u16 hh, hl;
            cvt_hl(h2v, hh, hl);
            const int idx = (cur * 16 + bg) * 4096 + so_base;
            st_agent_u16(&B2h[idx], hh);
            st_agent_u16(&B2l[idx], hl);
        }
    }

    // final: publish h2(TT-1), stage, emit
    group_barrier(flags, bg, TT + 1);
    {
        const int curF = (TT - 1) & 1;
        if (wid == 0) {
            const u16* g = B2h + (curF * 16 + bg) * 4096;
            #pragma unroll
            for (int i = 0; i < 8; ++i) stage16(g + i * 512 + l * 8, &sB2h[0][0][0] + i * 512);
        } else if (wid == 1) {
            const u16* g = B2l + (curF * 16 + bg) * 4096;
            #pragma unroll
            for (int i = 0; i < 8; ++i) stage16(g + i * 512 + l * 8, &sB2l[0][0][0] + i * 512);
        }
        __syncthreads();
        if (emitWG) {
            const float h0 = __uint_as_float((u32)(((const u16*)sB2h)[eo0]) << 16)
                           + __uint_as_float((u32)(((const u16*)sB2l)[eo0]) << 16);
            const float h1v = __uint_as_float((u32)(((const u16*)sB2h)[eo1]) << 16)
                            + __uint_as_float((u32)(((const u16*)sB2l)[eo1]) << 16);
            emit_outg(h0, h1v, W_out, redsc, boV, out + ro * (TT * DDIM) + (TT - 1) * DDIM, tid);
        }
    }
}

extern "C" void kernel_launch(void* const* d_in, const int* in_sizes, int n_in,
                              void* d_out, int out_size, void* d_ws, size_t ws_size,
                              hipStream_t stream) {
    (void)in_sizes; (void)n_in; (void)out_size; (void)ws_size;
    const float* x     = (const float*)d_in[0];
    const float* W_ih1 = (const float*)d_in[1];
    const float* W_hh1 = (const float*)d_in[2];
    const float* b_ih1 = (const float*)d_in[3];
    const float* b_hh1 = (const float*)d_in[4];
    const float* W_ih2 = (const float*)d_in[5];
    const float* W_hh2 = (const float*)d_in[6];
    const float* b_ih2 = (const float*)d_in[7];
    const float* b_hh2 = (const float*)d_in[8];
    const float* W_out = (const float*)d_in[9];
    const float* b_out = (const float*)d_in[10];
    float* out = (float*)d_out;

    char* ws = (char*)d_ws;
    u16* flags = (u16*)ws;                         // 1024 * 2B = 2KB (tokens <= 1025 fit u16)
    u16* B1h = (u16*)(ws + 2048);                  // 256KB each: [2][16][4096 u16]
    u16* B1l = (u16*)(ws + 2048 + 262144);
    u16* B2h = (u16*)(ws + 2048 + 524288);
    u16* B2l = (u16*)(ws + 2048 + 786432);         // total 1,050,624 B (= R10's proven footprint)

    // only flags need zeroing (slabs fully written before any read)
    hipMemsetAsync(d_ws, 0, 2048, stream);

    hipLaunchKernelGGL(lstm_persist, dim3(1024), dim3(192), 0, stream,
                       x, W_ih1, W_hh1, b_ih1, b_hh1,
                       W_ih2, W_hh2, b_ih2, b_hh2,
                       W_out, b_out, out, flags, B1h, B1l, B2h, B2l);
}

// Round 13
// 5852.755 us; speedup vs baseline: 2.5046x; 2.5046x over previous
//
#include <hip/hip_runtime.h>

#define TT 1024
#define DDIM 6
#define HH 256
#define AGSCOPE __HIP_MEMORY_SCOPE_AGENT

typedef float f4v __attribute__((ext_vector_type(4)));
typedef float f2v __attribute__((ext_vector_type(2)));
typedef short s8v __attribute__((ext_vector_type(8)));
typedef unsigned int u32;
typedef unsigned short u16;

// grid: 512 blocks = 16 batch-domains (bg = blk>>5, 16 batches) x 32 unit-groups (gg = blk&31).
// block: 128 threads = 2 waves (gh = wid). Each wave: 16 gate-rows (rows = unit*4+gate) x 16
// batches x FULL K, 3 independent bf16 plane chains, combine (aA+aB)+aC -> per-output arithmetic
// BIT-IDENTICAL to R8/R12 (the only measured-safe numerics; fp16 and K-split both fail).
// 2 blocks/CU (128thr, launch_bounds(128,1) -> k=2) with bg differing by 8 -> two independent
// barrier domains per CU: while one waits at barrier/stage, the other's waves (on the CU's other
// SIMDs) keep issuing MFMAs (R10-proven lever, without its fp16 cost).
// Slabs [2 dbuf][16 bg][4096 u16], idx(u,b) = (u>>5)*512 + ((u>>3)&3)*128 + b*8 + (u&7);
// frag-linear identity copy (k == u for the consumer); stage via global_load_lds aux=17
// (sc0|sc1, L3-fresh); write-through agent stores; flag barrier; no invalidates (R8-proven).

__device__ __forceinline__ float sigf(float x) {
    return __builtin_amdgcn_rcpf(1.0f + __expf(-x));
}
__device__ __forceinline__ float tanhf_fast(float x) {
    return fmaf(2.0f, __builtin_amdgcn_rcpf(1.0f + __expf(-2.0f * x)), -1.0f);
}
__device__ __forceinline__ void st_agent_u16(u16* p, u16 v) {
    __hip_atomic_store(p, v, __ATOMIC_RELAXED, AGSCOPE);
}

#define MFMA(a, b, c) __builtin_amdgcn_mfma_f32_16x16x32_bf16(a, b, c, 0, 0, 0)

// f32 -> bf16 hi (RNE) + bf16 lo (RNE of residual)  [R8 verbatim]
__device__ __forceinline__ void cvt_hl(float v, u16& hi, u16& lo) {
    u32 u = __float_as_uint(v);
    u32 r = (u + 0x7fffu + ((u >> 16) & 1u)) & 0xffff0000u;
    hi = (u16)(r >> 16);
    float lof = v - __uint_as_float(r);
    u32 u2 = __float_as_uint(lof);
    lo = (u16)((u2 + 0x7fffu + ((u2 >> 16) & 1u)) >> 16);
}
__device__ __forceinline__ void pack8_hl(const float* __restrict__ p, s8v& hi, s8v& lo) {
    #pragma unroll
    for (int j = 0; j < 8; ++j) {
        u16 h, l;
        cvt_hl(p[j], h, l);
        hi[j] = (short)h;
        lo[j] = (short)l;
    }
}

// async 16B/lane global->LDS copy; aux=17 = sc0|sc1 (read at L3 coherence point)
__device__ __forceinline__ void stage16(const u16* g, u16* lds) {
    __builtin_amdgcn_global_load_lds(
        (const __attribute__((address_space(1))) u32*)g,
        (__attribute__((address_space(3))) u32*)lds, 16, 0, 17);
}

__device__ __forceinline__ void group_barrier(int* flags, int bg, int token) {
    __syncthreads();                      // drains vmcnt -> h stores at L3
    asm volatile("" ::: "memory");
    if (threadIdx.x == 0) {
        __hip_atomic_store(&flags[blockIdx.x], token, __ATOMIC_RELAXED, AGSCOPE);
    }
    if (threadIdx.x < 32) {               // 32 peers share bg
        while (__hip_atomic_load(&flags[(bg << 5) + (int)threadIdx.x], __ATOMIC_RELAXED,
                                 AGSCOPE) < token) {
            __builtin_amdgcn_s_sleep(1);
        }
    }
    __syncthreads();
    asm volatile("" ::: "memory");
}

// 128-thread emit: thread covers units u=tid and u=tid+128 (output-side only; regroup-safe)
__device__ __forceinline__ void emit_out2(float h0, float h1v,
                                          const float (*Wo)[256],
                                          float (*redsc)[8],
                                          float boV,
                                          float* __restrict__ op, int tid) {
    float p0 = Wo[0][tid] * h0 + Wo[0][tid + 128] * h1v;
    float p1 = Wo[1][tid] * h0 + Wo[1][tid + 128] * h1v;
    float p2 = Wo[2][tid] * h0 + Wo[2][tid + 128] * h1v;
    float p3 = Wo[3][tid] * h0 + Wo[3][tid + 128] * h1v;
    float p4 = Wo[4][tid] * h0 + Wo[4][tid + 128] * h1v;
    float p5 = Wo[5][tid] * h0 + Wo[5][tid + 128] * h1v;
    #pragma unroll
    for (int off = 1; off < 64; off <<= 1) {
        p0 += __shfl_xor(p0, off);
        p1 += __shfl_xor(p1, off);
        p2 += __shfl_xor(p2, off);
        p3 += __shfl_xor(p3, off);
        p4 += __shfl_xor(p4, off);
        p5 += __shfl_xor(p5, off);
    }
    const int w = tid >> 6;
    if ((tid & 63) == 0) {
        redsc[w][0] = p0; redsc[w][1] = p1; redsc[w][2] = p2;
        redsc[w][3] = p3; redsc[w][4] = p4; redsc[w][5] = p5;
    }
    __syncthreads();
    if (tid < 6) {
        op[tid] = redsc[0][tid] + redsc[1][tid] + boV;
    }
}

__global__ __launch_bounds__(128, 1) void lstm_persist(
    const float* __restrict__ x,
    const float* __restrict__ W_ih1, const float* __restrict__ W_hh1,
    const float* __restrict__ b_ih1, const float* __restrict__ b_hh1,
    const float* __restrict__ W_ih2, const float* __restrict__ W_hh2,
    const float* __restrict__ b_ih2, const float* __restrict__ b_hh2,
    const float* __restrict__ W_out, const float* __restrict__ b_out,
    float* __restrict__ out,
    int* __restrict__ flags,
    u16* __restrict__ B1h, u16* __restrict__ B1l,
    u16* __restrict__ B2h, u16* __restrict__ B2l)
{
    __shared__ u16 sB1h[8][64][8], sB1l[8][64][8];   // 8KB each, frag-linear
    __shared__ u16 sB2h[8][64][8], sB2l[8][64][8];
    __shared__ float Wo[6][256];
    __shared__ float redsc[2][8];

    const int tid = threadIdx.x;
    const int blk = blockIdx.x;
    const int gg  = blk & 31;              // unit-group (8 units)
    const int bg  = blk >> 5;              // batch-domain (16 batches)
    const int wid = tid >> 6;              // wave = gh (unit half)
    const int l   = tid & 63;
    const int gh  = wid;
    const int kl  = (l >> 4) << 3;         // lane k-offset within 32-chunk
    // A-operand lane (R6-verified): row r32 within 32 gate-rows; row = du*4 + gate
    const int r32  = (gh << 4) + (l & 15);
    const int gr_a = (r32 & 3) * HH + (gg << 3) + (r32 >> 2);
    // D-owner lane: unit du, batch db
    const int du       = (gh << 2) + (l >> 4);
    const int db       = l & 15;
    const int unit_abs = (gg << 3) + du;
    const int db_abs   = (bg << 4) + db;
    const bool emitWG  = (gg < 16);
    const int ro       = (bg << 4) + (gg & 15);   // emitted batch row (emitWG only)

    // owner store u16 offset inside a slab
    const int so_base = (unit_abs >> 5) * 512 + ((unit_abs >> 3) & 3) * 128
                      + db * 8 + (unit_abs & 7);
    // emit read offsets for units u=tid and u=tid+128 (b_local = gg&15)
    const int eo0 = (tid >> 5) * 512 + (((tid >> 3) & 3) * 128) + (gg & 15) * 8 + (tid & 7);
    const int u1  = tid + 128;
    const int eo1 = (u1 >> 5) * 512 + (((u1 >> 3) & 3) * 128) + (gg & 15) * 8 + (u1 & 7);

    // ---- prologue: zero slabs (h(0)=0), load Wo ----
    for (int i = tid; i < 2048; i += 128) {
        ((u32*)sB1h)[i] = 0u; ((u32*)sB1l)[i] = 0u;
        ((u32*)sB2h)[i] = 0u; ((u32*)sB2l)[i] = 0u;
    }
    for (int i = tid; i < 6 * 256; i += 128) Wo[i >> 8][i & 255] = W_out[i];

    // ---- A-fragments: full K, bf16 hi/lo planes in VGPRs (R8 structure & bits) ----
    s8v A1h[8], A1l[8], A2h[16], A2l[16];
    #pragma unroll
    for (int c = 0; c < 8; ++c)
        pack8_hl(W_hh1 + gr_a * HH + c * 32 + kl, A1h[c], A1l[c]);
    #pragma unroll
    for (int c = 0; c < 8; ++c)
        pack8_hl(W_ih2 + gr_a * HH + c * 32 + kl, A2h[c], A2l[c]);
    #pragma unroll
    for (int c = 0; c < 8; ++c)
        pack8_hl(W_hh2 + gr_a * HH + c * 32 + kl, A2h[8 + c], A2l[8 + c]);

    // ---- D-owner constants ----
    float b1a[4], b2a[4], Wxr[4][6];
    #pragma unroll
    for (int g = 0; g < 4; ++g) {
        const int gr = g * HH + unit_abs;
        b1a[g] = b_ih1[gr] + b_hh1[gr];
        b2a[g] = b_ih2[gr] + b_hh2[gr];
        #pragma unroll
        for (int d = 0; d < 6; ++d) Wxr[g][d] = W_ih1[gr * DDIM + d];
    }
    const float boV = (tid < 6) ? b_out[tid] : 0.0f;
    float c1 = 0.0f, c2 = 0.0f;

    const float* xbase = x + (size_t)db_abs * (TT * DDIM);
    f2v xA = *(const f2v*)(xbase);
    f2v xB = *(const f2v*)(xbase + 2);
    f2v xC = *(const f2v*)(xbase + 4);
    __syncthreads();

    #pragma unroll 1
    for (int t = 0; t < TT; ++t) {
        const int cur = t & 1, prv = cur ^ 1;

        // ---- P1: layer-1 full-K MFMAs (B = h1(t-1)), 3 indep chains (R8 grouping) ----
        f4v aA = {0.f,0.f,0.f,0.f}, aB = {0.f,0.f,0.f,0.f}, aC = {0.f,0.f,0.f,0.f};
        #pragma unroll
        for (int c = 0; c < 8; ++c) {
            const s8v vhi = *(const s8v*)&sB1h[c][l][0];
            const s8v vlo = *(const s8v*)&sB1l[c][l][0];
            aA = MFMA(A1h[c], vhi, aA);
            aB = MFMA(A1h[c], vlo, aB);
            aC = MFMA(A1l[c], vhi, aC);
        }
        {
            const f4v acc = (aA + aB) + aC;         // R8 combine order
            float ga[4];
            #pragma unroll
            for (int g = 0; g < 4; ++g) {
                float a = acc[g] + b1a[g];
                a = fmaf(Wxr[g][0], xA.x, a); a = fmaf(Wxr[g][1], xA.y, a);
                a = fmaf(Wxr[g][2], xB.x, a); a = fmaf(Wxr[g][3], xB.y, a);
                a = fmaf(Wxr[g][4], xC.x, a); a = fmaf(Wxr[g][5], xC.y, a);
                ga[g] = a;
            }
            const float i1 = sigf(ga[0]), f1 = sigf(ga[1]);
            const float g1 = tanhf_fast(ga[2]), o1 = sigf(ga[3]);
            c1 = fmaf(f1, c1, i1 * g1);
            const float h1v = o1 * tanhf_fast(c1);
            u16 hh, hl;
            cvt_hl(h1v, hh, hl);
            const int idx = (cur * 16 + bg) * 4096 + so_base;
            st_agent_u16(&B1h[idx], hh);
            st_agent_u16(&B1l[idx], hl);
        }

        // publish h1(t) (+ h2(t-1) stored last step)
        group_barrier(flags, bg, t + 1);

        // ---- stage slabs: wave0 -> hi planes, wave1 -> lo planes ----
        if (wid == 0) {
            const u16* g1p = B1h + (cur * 16 + bg) * 4096;
            #pragma unroll
            for (int i = 0; i < 8; ++i) stage16(g1p + i * 512 + l * 8, &sB1h[0][0][0] + i * 512);
            if (t > 0) {
                const u16* g2p = B2h + (prv * 16 + bg) * 4096;
                #pragma unroll
                for (int i = 0; i < 8; ++i) stage16(g2p + i * 512 + l * 8, &sB2h[0][0][0] + i * 512);
            }
        } else {
            const u16* g1p = B1l + (cur * 16 + bg) * 4096;
            #pragma unroll
            for (int i = 0; i < 8; ++i) stage16(g1p + i * 512 + l * 8, &sB1l[0][0][0] + i * 512);
            if (t > 0) {
                const u16* g2p = B2l + (prv * 16 + bg) * 4096;
                #pragma unroll
                for (int i = 0; i < 8; ++i) stage16(g2p + i * 512 + l * 8, &sB2l[0][0][0] + i * 512);
            }
        }

        // x(t+1) register prefetch (overlaps stage latency)
        f2v xAn = xA, xBn = xB, xCn = xC;
        if (t + 1 < TT) {
            const float* xnp = xbase + (t + 1) * DDIM;
            xAn = *(const f2v*)(xnp);
            xBn = *(const f2v*)(xnp + 2);
            xCn = *(const f2v*)(xnp + 4);
        }

        __syncthreads();   // stage complete (vmcnt drained)

        // ---- emit out(t-1) from staged LDS slab ----
        if (emitWG && t > 0) {
            const float h0 = __uint_as_float((u32)(((const u16*)sB2h)[eo0]) << 16)
                           + __uint_as_float((u32)(((const u16*)sB2l)[eo0]) << 16);
            const float h1v = __uint_as_float((u32)(((const u16*)sB2h)[eo1]) << 16)
                            + __uint_as_float((u32)(((const u16*)sB2l)[eo1]) << 16);
            emit_out2(h0, h1v, Wo, redsc, boV, out + ro * (TT * DDIM) + (t - 1) * DDIM, tid);
        }

        // ---- P5: layer-2 full: [h1(t) (sB1); h2(t-1) (sB2)], 3 indep chains ----
        f4v eA = {0.f,0.f,0.f,0.f}, eB = {0.f,0.f,0.f,0.f}, eC = {0.f,0.f,0.f,0.f};
        #pragma unroll
        for (int c = 0; c < 8; ++c) {
            const s8v vhi = *(const s8v*)&sB1h[c][l][0];
            const s8v vlo = *(const s8v*)&sB1l[c][l][0];
            eA = MFMA(A2h[c], vhi, eA);
            eB = MFMA(A2h[c], vlo, eB);
            eC = MFMA(A2l[c], vhi, eC);
        }
        #pragma unroll
        for (int c = 0; c < 8; ++c) {
            const s8v vhi = *(const s8v*)&sB2h[c][l][0];
            const s8v vlo = *(const s8v*)&sB2l[c][l][0];
            eA = MFMA(A2h[8 + c], vhi, eA);
            eB = MFMA(A2h[8 + c], vlo, eB);
            eC = MFMA(A2l[8 + c], vhi, eC);
        }
        {
            const f4v acc2 = (eA + eB) + eC;        // R8 combine order
            const float i2  = sigf(acc2[0] + b2a[0]);
            const float f2g = sigf(acc2[1] + b2a[1]);
            const float g2  = tanhf_fast(acc2[2] + b2a[2]);
            const float o2  = sigf(acc2[3] + b2a[3]);
            c2 = fmaf(f2g, c2, i2 * g2);
            const float h2v = o2 * tanhf_fast(c2);
            u16 hh, hl;
            cvt_hl(h2v, hh, hl);
            const int idx = (cur * 16 + bg) * 4096 + so_base;
            st_agent_u16(&B2h[idx], hh);
            st_agent_u16(&B2l[idx], hl);
        }

        xA = xAn; xB = xBn; xC = xCn;
    }

    // final: publish h2(TT-1), stage, emit
    group_barrier(flags, bg, TT + 1);
    {
        const int curF = (TT - 1) & 1;
        if (wid == 0) {
            const u16* g = B2h + (curF * 16 + bg) * 4096;
            #pragma unroll
            for (int i = 0; i < 8; ++i) stage16(g + i * 512 + l * 8, &sB2h[0][0][0] + i * 512);
        } else {
            const u16* g = B2l + (curF * 16 + bg) * 4096;
            #pragma unroll
            for (int i = 0; i < 8; ++i) stage16(g + i * 512 + l * 8, &sB2l[0][0][0] + i * 512);
        }
        __syncthreads();
        if (emitWG) {
            const float h0 = __uint_as_float((u32)(((const u16*)sB2h)[eo0]) << 16)
                           + __uint_as_float((u32)(((const u16*)sB2l)[eo0]) << 16);
            const float h1v = __uint_as_float((u32)(((const u16*)sB2h)[eo1]) << 16)
                            + __uint_as_float((u32)(((const u16*)sB2l)[eo1]) << 16);
            emit_out2(h0, h1v, Wo, redsc, boV, out + ro * (TT * DDIM) + (TT - 1) * DDIM, tid);
        }
    }
}

extern "C" void kernel_launch(void* const* d_in, const int* in_sizes, int n_in,
                              void* d_out, int out_size, void* d_ws, size_t ws_size,
                              hipStream_t stream) {
    (void)in_sizes; (void)n_in; (void)out_size; (void)ws_size;
    const float* x     = (const float*)d_in[0];
    const float* W_ih1 = (const float*)d_in[1];
    const float* W_hh1 = (const float*)d_in[2];
    const float* b_ih1 = (const float*)d_in[3];
    const float* b_hh1 = (const float*)d_in[4];
    const float* W_ih2 = (const float*)d_in[5];
    const float* W_hh2 = (const float*)d_in[6];
    const float* b_ih2 = (const float*)d_in[7];
    const float* b_hh2 = (const float*)d_in[8];
    const float* W_out = (const float*)d_in[9];
    const float* b_out = (const float*)d_in[10];
    float* out = (float*)d_out;

    char* ws = (char*)d_ws;
    int* flags = (int*)ws;                         // 512 * 4B = 2KB
    u16* B1h = (u16*)(ws + 2048);                  // 256KB each: [2][16][4096 u16]
    u16* B1l = (u16*)(ws + 2048 + 262144);
    u16* B2h = (u16*)(ws + 2048 + 524288);
    u16* B2l = (u16*)(ws + 2048 + 786432);

    // only flags need zeroing (slabs fully written before any read)
    hipMemsetAsync(d_ws, 0, 2048, stream);

    hipLaunchKernelGGL(lstm_persist, dim3(512), dim3(128), 0, stream,
                       x, W_ih1, W_hh1, b_ih1, b_hh1,
                       W_ih2, W_hh2, b_ih2, b_hh2,
                       W_out, b_out, out, flags, B1h, B1l, B2h, B2l);
}

// Round 15
// 5338.182 us; speedup vs baseline: 2.7461x; 1.0964x over previous
//
#include <hip/hip_runtime.h>

#define TT 1024
#define DDIM 6
#define HH 256
#define AGSCOPE __HIP_MEMORY_SCOPE_AGENT
#define LOSC 4.8828125e-4f   // 2^-11: lo-plane descale

typedef float    f4v __attribute__((ext_vector_type(4)));
typedef float    f2v __attribute__((ext_vector_type(2)));
typedef _Float16 hf;
typedef hf       h8v __attribute__((ext_vector_type(8)));
typedef unsigned int u32;

// R10 VERBATIM REVERT (best fully-validated configuration: 5.17 ms, passed pre+post timing).
// grid: 512 blocks = 16 batch-groups (bg = blk>>5, 16 batches) x 32 unit-groups (gg = blk&31).
// 2 blocks/CU (blk, blk+256 -> bg differs by 8): anti-phased barrier domains share SIMDs.
// block: 4 waves (gh: unit-half, kh: K-half); K-split partials reduced via pscr in LDS.
// Precision: fp16 hi + 2^11-scaled fp16 lo split of W and h; gates = accHH + 2^-11*(accHL+accLH).
// Slabs/stage/barrier protocol from R7-R9 (frag-linear identity copy, aux=17 stage,
// write-through agent stores, flag barrier inside all-wave group_barrier, no invalidates).

__device__ __forceinline__ float sigf(float x) {
    return __builtin_amdgcn_rcpf(1.0f + __expf(-x));
}
__device__ __forceinline__ float tanhf_fast(float x) {
    return fmaf(2.0f, __builtin_amdgcn_rcpf(1.0f + __expf(-2.0f * x)), -1.0f);
}
__device__ __forceinline__ void st_agent_u16(unsigned short* p, unsigned short v) {
    __hip_atomic_store(p, v, __ATOMIC_RELAXED, AGSCOPE);
}

#define MFMA(a, b, c) __builtin_amdgcn_mfma_f32_16x16x32_f16(a, b, c, 0, 0, 0)

// f32 -> fp16 hi (RNE) + fp16 lo scaled by 2^11 (keeps lo in normal range)
__device__ __forceinline__ void cvt_hl(float v, hf& hi, hf& lo) {
    hi = (hf)v;
    lo = (hf)((v - (float)hi) * 2048.0f);
}
__device__ __forceinline__ void pack8_hl(const float* __restrict__ p, h8v& hi, h8v& lo) {
    #pragma unroll
    for (int j = 0; j < 8; ++j) {
        hf h, l;
        cvt_hl(p[j], h, l);
        hi[j] = h;
        lo[j] = l;
    }
}

// async 16B/lane global->LDS copy; aux=17 = sc0|sc1 (read at L3 coherence point)
__device__ __forceinline__ void stage16(const unsigned short* g, unsigned short* lds) {
    __builtin_amdgcn_global_load_lds(
        (const __attribute__((address_space(1))) u32*)g,
        (__attribute__((address_space(3))) u32*)lds, 16, 0, 17);
}

__device__ __forceinline__ void group_barrier(int* flags, int bg, int token) {
    __syncthreads();                      // drains vmcnt -> h stores at L3
    asm volatile("" ::: "memory");
    if (threadIdx.x == 0) {
        __hip_atomic_store(&flags[blockIdx.x], token, __ATOMIC_RELAXED, AGSCOPE);
    }
    if (threadIdx.x < 32) {               // 32 peers share bg
        while (__hip_atomic_load(&flags[(bg << 5) + (int)threadIdx.x], __ATOMIC_RELAXED,
                                 AGSCOPE) < token) {
            __builtin_amdgcn_s_sleep(1);
        }
    }
    __syncthreads();
    asm volatile("" ::: "memory");
}

__device__ __forceinline__ void emit_out(float hval,
                                         const float (*Wo)[256],
                                         float (*redsc)[8],
                                         float boV,
                                         float* __restrict__ op, int tid) {
    float p0 = Wo[0][tid] * hval;
    float p1 = Wo[1][tid] * hval;
    float p2 = Wo[2][tid] * hval;
    float p3 = Wo[3][tid] * hval;
    float p4 = Wo[4][tid] * hval;
    float p5 = Wo[5][tid] * hval;
    #pragma unroll
    for (int off = 1; off < 64; off <<= 1) {
        p0 += __shfl_xor(p0, off);
        p1 += __shfl_xor(p1, off);
        p2 += __shfl_xor(p2, off);
        p3 += __shfl_xor(p3, off);
        p4 += __shfl_xor(p4, off);
        p5 += __shfl_xor(p5, off);
    }
    const int wid = tid >> 6;
    if ((tid & 63) == 0) {
        redsc[wid][0] = p0; redsc[wid][1] = p1; redsc[wid][2] = p2;
        redsc[wid][3] = p3; redsc[wid][4] = p4; redsc[wid][5] = p5;
    }
    __syncthreads();
    if (tid < 6) {
        op[tid] = redsc[0][tid] + redsc[1][tid] + redsc[2][tid] + redsc[3][tid] + boV;
    }
}

__global__ __launch_bounds__(256, 2) void lstm_persist(
    const float* __restrict__ x,
    const float* __restrict__ W_ih1, const float* __restrict__ W_hh1,
    const float* __restrict__ b_ih1, const float* __restrict__ b_hh1,
    const float* __restrict__ W_ih2, const float* __restrict__ W_hh2,
    const float* __restrict__ b_ih2, const float* __restrict__ b_hh2,
    const float* __restrict__ W_out, const float* __restrict__ b_out,
    float* __restrict__ out,
    int* __restrict__ flags,
    unsigned short* __restrict__ B1h, unsigned short* __restrict__ B1l,
    unsigned short* __restrict__ B2h, unsigned short* __restrict__ B2l)
{
    __shared__ unsigned short sB1h[8][64][8], sB1l[8][64][8];   // 8KB each, frag-linear
    __shared__ unsigned short sB2h[8][64][8], sB2l[8][64][8];
    __shared__ hf    sA2l[4][8][64][8];          // layer-2 A lo-plane frags, per-wave linear (32KB)
    __shared__ float sWx[4][8][8];               // x-weights [gate][du][d]
    __shared__ float Wo[6][256];
    __shared__ float redsc[4][8];
    __shared__ f4v pscrA[2][64], pscrB[2][64];   // K-half partial sums (P1 / P5)

    const int tid = threadIdx.x;
    const int blk = blockIdx.x;
    const int gg  = blk & 31;              // unit-group (8 units)
    const int bg  = blk >> 5;              // batch-group (16 batches)
    const int wid = tid >> 6;
    const int l   = tid & 63;
    const int gh  = wid >> 1;              // unit half (tile)
    const int kh  = wid & 1;               // K half / layer-2 matrix select
    const int kl  = (l >> 4) << 3;         // lane k-offset within 32-chunk
    // A-operand lane (R6-verified): row r32 within 32 gate-rows; row = du*4 + gate
    const int r32  = (gh << 4) + (l & 15);
    const int gr_a = (r32 & 3) * HH + (gg << 3) + (r32 >> 2);
    // D-owner lane (kh==0 waves): unit du, batch db
    const int du       = (gh << 2) + (l >> 4);
    const int db       = l & 15;
    const int unit_abs = (gg << 3) + du;
    const int db_abs   = (bg << 4) + db;
    const int ro       = (bg << 4) + (gg & 15);   // emitted batch row (gg<16 WGs only)

    // owner store u16 offset inside a slab: (u>>5)*512 + ((u>>3)&3)*128 + b*8 + (u&7)
    const int so_base = (unit_abs >> 5) * 512 + ((unit_abs >> 3) & 3) * 128
                      + db * 8 + (unit_abs & 7);
    // emit read (LDS, identity copy): b_local = gg&15, u = tid
    const int eo = (tid >> 5) * 512 + (((tid >> 3) & 3) * 128) + (gg & 15) * 8 + (tid & 7);

    // ---- prologue: zero slabs (h(0)=0), load Wo, x-weights ----
    for (int i = tid; i < 2048; i += 256) {
        ((u32*)sB1h)[i] = 0u; ((u32*)sB1l)[i] = 0u;
        ((u32*)sB2h)[i] = 0u; ((u32*)sB2l)[i] = 0u;
    }
    for (int i = tid; i < 6 * 256; i += 256) Wo[i >> 8][i & 255] = W_out[i];
    for (int i = tid; i < 192; i += 256) {
        const int r = i / 6, d = i - r * 6;          // r = gate*8 + du_
        sWx[r >> 3][r & 7][d] = W_ih1[((r >> 3) * HH + (gg << 3) + (r & 7)) * DDIM + d];
    }

    // ---- A-fragments: hi planes in VGPR; layer-2 lo planes in LDS (per-wave, own-lane) ----
    h8v A1h[4], A1l[4], A2h[8];
    #pragma unroll
    for (int c = 0; c < 4; ++c) {
        const int cc = (kh << 2) + c;
        pack8_hl(W_hh1 + gr_a * HH + cc * 32 + kl, A1h[c], A1l[c]);
    }
    {
        const float* W2 = kh ? W_hh2 : W_ih2;    // kh0: h1(t) input, kh1: h2(t-1) input
        #pragma unroll
        for (int c = 0; c < 8; ++c) {
            h8v hi, lo;
            pack8_hl(W2 + gr_a * HH + c * 32 + kl, hi, lo);
            A2h[c] = hi;
            *(h8v*)&sA2l[wid][c][l][0] = lo;     // own-lane write, read back by same lane
        }
    }

    // ---- D-owner constants ----
    float b1a[4], b2a[4];
    #pragma unroll
    for (int g = 0; g < 4; ++g) {
        const int gr = g * HH + unit_abs;
        b1a[g] = b_ih1[gr] + b_hh1[gr];
        b2a[g] = b_ih2[gr] + b_hh2[gr];
    }
    const float boV = (tid < 6) ? b_out[tid] : 0.0f;
    float c1 = 0.0f, c2 = 0.0f;

    const float* xbase = x + (size_t)db_abs * (TT * DDIM);
    f2v xA = {0.f,0.f}, xB = {0.f,0.f}, xC = {0.f,0.f};
    if (kh == 0) {
        xA = *(const f2v*)(xbase);
        xB = *(const f2v*)(xbase + 2);
        xC = *(const f2v*)(xbase + 4);
    }
    __syncthreads();

    #pragma unroll 1
    for (int t = 0; t < TT; ++t) {
        const int cur = t & 1, prv = cur ^ 1;

        // ---- P1: layer-1 (this wave's K-half), 3 chains: HH, H*lo', lo'*H ----
        f4v aA = {0.f,0.f,0.f,0.f}, aB = {0.f,0.f,0.f,0.f}, aC = {0.f,0.f,0.f,0.f};
        #pragma unroll
        for (int c = 0; c < 4; ++c) {
            const int cc = (kh << 2) + c;
            const h8v vhi = *(const h8v*)&sB1h[cc][l][0];
            const h8v vlo = *(const h8v*)&sB1l[cc][l][0];
            aA = MFMA(A1h[c], vhi, aA);
            aB = MFMA(A1h[c], vlo, aB);
            aC = MFMA(A1l[c], vhi, aC);
        }
        {
            const f4v p1 = aA + (aB + aC) * LOSC;
            if (kh) pscrA[gh][l] = p1;
            __syncthreads();
            if (!kh) {
                const f4v acc = p1 + pscrA[gh][l];
                float ga[4];
                #pragma unroll
                for (int g = 0; g < 4; ++g) {
                    float a = acc[g] + b1a[g];
                    a = fmaf(sWx[g][du][0], xA.x, a); a = fmaf(sWx[g][du][1], xA.y, a);
                    a = fmaf(sWx[g][du][2], xB.x, a); a = fmaf(sWx[g][du][3], xB.y, a);
                    a = fmaf(sWx[g][du][4], xC.x, a); a = fmaf(sWx[g][du][5], xC.y, a);
                    ga[g] = a;
                }
                const float i1 = sigf(ga[0]), f1 = sigf(ga[1]);
                const float g1 = tanhf_fast(ga[2]), o1 = sigf(ga[3]);
                c1 = fmaf(f1, c1, i1 * g1);
                const float h1v = o1 * tanhf_fast(c1);
                hf hh, hl;
                cvt_hl(h1v, hh, hl);
                const int idx = (cur * 16 + bg) * 4096 + so_base;
                st_agent_u16(&B1h[idx], __builtin_bit_cast(unsigned short, hh));
                st_agent_u16(&B1l[idx], __builtin_bit_cast(unsigned short, hl));
            }
        }

        // publish h1(t) (+ h2(t-1) stored last step)
        group_barrier(flags, bg, t + 1);

        // ---- stage slabs (1 array per wave, 8 insts each) ----
        if (wid == 0) {
            const unsigned short* g = B1h + (cur * 16 + bg) * 4096;
            #pragma unroll
            for (int i = 0; i < 8; ++i) stage16(g + i * 512 + l * 8, &sB1h[0][0][0] + i * 512);
        } else if (wid == 1) {
            const unsigned short* g = B1l + (cur * 16 + bg) * 4096;
            #pragma unroll
            for (int i = 0; i < 8; ++i) stage16(g + i * 512 + l * 8, &sB1l[0][0][0] + i * 512);
        } else if (wid == 2) {
            if (t > 0) {
                const unsigned short* g = B2h + (prv * 16 + bg) * 4096;
                #pragma unroll
                for (int i = 0; i < 8; ++i) stage16(g + i * 512 + l * 8, &sB2h[0][0][0] + i * 512);
            }
        } else {
            if (t > 0) {
                const unsigned short* g = B2l + (prv * 16 + bg) * 4096;
                #pragma unroll
                for (int i = 0; i < 8; ++i) stage16(g + i * 512 + l * 8, &sB2l[0][0][0] + i * 512);
            }
        }

        // x(t+1) register prefetch (kh0 waves; overlaps stage latency)
        f2v xAn = xA, xBn = xB, xCn = xC;
        if (kh == 0 && t + 1 < TT) {
            const float* xnp = xbase + (t + 1) * DDIM;
            xAn = *(const f2v*)(xnp);
            xBn = *(const f2v*)(xnp + 2);
            xCn = *(const f2v*)(xnp + 4);
        }

        __syncthreads();   // stage complete

        // ---- emit out(t-1) from staged LDS slab (emitting WGs only; gg uniform) ----
        if (gg < 16 && t > 0) {
            const hf ehi = __builtin_bit_cast(hf, ((const unsigned short*)sB2h)[eo]);
            const hf elo = __builtin_bit_cast(hf, ((const unsigned short*)sB2l)[eo]);
            const float hval = (float)ehi + LOSC * (float)elo;
            emit_out(hval, Wo, redsc, boV, out + ro * (TT * DDIM) + (t - 1) * DDIM, tid);
        }

        // ---- P5: layer-2; kh0: W_ih2 x h1(t) (sB1), kh1: W_hh2 x h2(t-1) (sB2) ----
        {
            const unsigned short* shp = kh ? &sB2h[0][0][0] : &sB1h[0][0][0];
            const unsigned short* slp = kh ? &sB2l[0][0][0] : &sB1l[0][0][0];
            f4v eA = {0.f,0.f,0.f,0.f}, eB = {0.f,0.f,0.f,0.f}, eC = {0.f,0.f,0.f,0.f};
            #pragma unroll
            for (int c = 0; c < 8; ++c) {
                const h8v vhi = *(const h8v*)(shp + c * 512 + l * 8);
                const h8v vlo = *(const h8v*)(slp + c * 512 + l * 8);
                const h8v Al  = *(const h8v*)&sA2l[wid][c][l][0];
                eA = MFMA(A2h[c], vhi, eA);
                eB = MFMA(A2h[c], vlo, eB);
                eC = MFMA(Al,     vhi, eC);
            }
            const f4v p5 = eA + (eB + eC) * LOSC;
            if (kh) pscrB[gh][l] = p5;
            __syncthreads();
            if (!kh) {
                const f4v acc2 = p5 + pscrB[gh][l];
                const float i2  = sigf(acc2[0] + b2a[0]);
                const float f2g = sigf(acc2[1] + b2a[1]);
                const float g2  = tanhf_fast(acc2[2] + b2a[2]);
                const float o2  = sigf(acc2[3] + b2a[3]);
                c2 = fmaf(f2g, c2, i2 * g2);
                const float h2v = o2 * tanhf_fast(c2);
                hf hh, hl;
                cvt_hl(h2v, hh, hl);
                const int idx = (cur * 16 + bg) * 4096 + so_base;
                st_agent_u16(&B2h[idx], __builtin_bit_cast(unsigned short, hh));
                st_agent_u16(&B2l[idx], __builtin_bit_cast(unsigned short, hl));
            }
        }

        xA = xAn; xB = xBn; xC = xCn;
    }

    // final: publish h2(TT-1), stage, emit
    group_barrier(flags, bg, TT + 1);
    {
        const int curF = (TT - 1) & 1;
        if (wid == 2) {
            const unsigned short* g = B2h + (curF * 16 + bg) * 4096;
            #pragma unroll
            for (int i = 0; i < 8; ++i) stage16(g + i * 512 + l * 8, &sB2h[0][0][0] + i * 512);
        } else if (wid == 3) {
            const unsigned short* g = B2l + (curF * 16 + bg) * 4096;
            #pragma unroll
            for (int i = 0; i < 8; ++i) stage16(g + i * 512 + l * 8, &sB2l[0][0][0] + i * 512);
        }
        __syncthreads();
        if (gg < 16) {
            const hf ehi = __builtin_bit_cast(hf, ((const unsigned short*)sB2h)[eo]);
            const hf elo = __builtin_bit_cast(hf, ((const unsigned short*)sB2l)[eo]);
            const float hval = (float)ehi + LOSC * (float)elo;
            emit_out(hval, Wo, redsc, boV, out + ro * (TT * DDIM) + (TT - 1) * DDIM, tid);
        }
    }
}

extern "C" void kernel_launch(void* const* d_in, const int* in_sizes, int n_in,
                              void* d_out, int out_size, void* d_ws, size_t ws_size,
                              hipStream_t stream) {
    (void)in_sizes; (void)n_in; (void)out_size; (void)ws_size;
    const float* x     = (const float*)d_in[0];
    const float* W_ih1 = (const float*)d_in[1];
    const float* W_hh1 = (const float*)d_in[2];
    const float* b_ih1 = (const float*)d_in[3];
    const float* b_hh1 = (const float*)d_in[4];
    const float* W_ih2 = (const float*)d_in[5];
    const float* W_hh2 = (const float*)d_in[6];
    const float* b_ih2 = (const float*)d_in[7];
    const float* b_hh2 = (const float*)d_in[8];
    const float* W_out = (const float*)d_in[9];
    const float* b_out = (const float*)d_in[10];
    float* out = (float*)d_out;

    char* ws = (char*)d_ws;
    int* flags = (int*)ws;                                        // 512 * 4B = 2KB
    unsigned short* B1h = (unsigned short*)(ws + 2048);           // 256KB each:
    unsigned short* B1l = (unsigned short*)(ws + 2048 + 262144);  // [2][16][4096 u16]
    unsigned short* B2h = (unsigned short*)(ws + 2048 + 524288);
    unsigned short* B2l = (unsigned short*)(ws + 2048 + 786432);

    // only flags need zeroing (slabs fully written before any read)
    hipMemsetAsync(d_ws, 0, 2048, stream);

    hipLaunchKernelGGL(lstm_persist, dim3(512), dim3(256), 0, stream,
                       x, W_ih1, W_hh1, b_ih1, b_hh1,
                       W_ih2, W_hh2, b_ih2, b_hh2,
                       W_out, b_out, out, flags, B1h, B1l, B2h, B2l);
}